// Round 2
// baseline (256.350 us; speedup 1.0000x reference)
//
#include <hip/hip_runtime.h>
#include <math.h>

// Problem constants (match reference)
constexpr int B = 256;
constexpr int T = 16384;
constexpr int K = 3;

// Speculative chunking: emit 256 steps after 512-step warm-up (proven R5/R6).
constexpr int CHUNK = 256;
constexpr int WARM  = 512;

// Conv tiling: 64 chains x 128 timesteps per block, 4 waves x 32 t each.
constexpr int CBT = 128;
constexpr int CWT = 32;

// R8: panel is now f32 (50 MB, was f64/100 MB). R6/R7 post-mortem: two
// opposite buffering schemes (register triple-buffer vs LDS-DMA with counted
// vmcnt, 36-72 loads in flight) tie at ~12 GB/s/CU -> the scan is served-rate
// bound (~3 TB/s system) not wave-latency bound. Lever = bytes + L3 residency:
// f32 panel halves read volume AND fits L3 next to u_out/s_out traffic
// (FETCH_SIZE 145 MB was the f64 panel round-tripping through HBM).
// Numerics: scan STATE stays f64; only W = (a - 0.05) is rounded once to f32
// (~3e-8), leak-accumulated ~1e-7 -- same order as the f64-kernel-vs-f32-
// reference perturbation that already passes.
//
// w32 panel layout [T/16][4 bg][12 q][64 lane] x 16B (float4):
// float4 q of lane i = stream floats (4q..4q+3) of chain (bg*64+i), stream
// ordered (t_local 0..15) x (ch 0..2). Lane-coalesced; the LDS image after
// global_load_lds is the identical linear 12 KB slab.

// ---------------------------------------------------------------------------
// Conv: causal k=8/16/32 in f64 (same tap order / fma / scale as R2-R7).
// Lane = chain, 32-double sliding ring window from LDS-staged x.
// Only the panel store changed: f32 values, f32 layout.
// ---------------------------------------------------------------------------
__global__ __launch_bounds__(256, 2) void conv_kernel(
    const float* __restrict__ x,
    const float* __restrict__ w0f,
    const float* __restrict__ w1f,
    const float* __restrict__ w2f,
    float*  __restrict__ u_out,   // [B][K][T] f32
    float*  __restrict__ w32)     // panel layout above
{
    const int blk = blockIdx.x;            // 512 blocks
    const int bgi = blk >> 7;              // 4 b-tiles
    const int t0  = (blk & 127) * CBT;     // 128 t-tiles
    const int b0  = bgi * 64;
    const int tid = threadIdx.x;

    __shared__ float sx[64][164];          // cols t0-32 .. t0+127, +4 pad (41 words: 2-way free)
    for (int k = tid; k < 64 * 40; k += 256) {
        const int r  = k / 40;
        const int c4 = k - r * 40;
        const int g  = t0 - 32 + 4 * c4;
        float4 v = make_float4(0.f, 0.f, 0.f, 0.f);
        if (g >= 0) v = *(const float4*)(x + (size_t)(b0 + r) * T + g);
        *(float4*)&sx[r][4 * c4] = v;
    }
    __syncthreads();

    const int lane    = tid & 63;
    const int w       = tid >> 6;
    const int t_start = t0 + CWT * w;

    double w0d[8], w1d[16], w2d[32];
#pragma unroll
    for (int i = 0; i < 8; ++i)  w0d[i] = (double)w0f[i];
#pragma unroll
    for (int i = 0; i < 16; ++i) w1d[i] = (double)w1f[i];
#pragma unroll
    for (int i = 0; i < 32; ++i) w2d[i] = (double)w2f[i];

    // ring window: win[t & 31] = x[chain][t]
    double win[32];
#pragma unroll
    for (int k = 1; k < 32; ++k) win[k] = (double)sx[lane][CWT * w + k];

    const double s8  = 1.0 / sqrt(8.0);
    const double s32 = 1.0 / sqrt(32.0);

    float fr0[16], fr1[16], fr2[16];
    float* uf = u_out + (size_t)(b0 + lane) * (3 * T);

#pragma unroll
    for (int j = 0; j < CWT; ++j) {
        win[j & 31] = (double)sx[lane][CWT * w + 32 + j];   // push x[t]
        double a0 = 0.0, a1 = 0.0, a2 = 0.0;
#pragma unroll
        for (int i = 0; i < 8; ++i)  a0 = fma(w0d[i], win[(j + 25 + i) & 31], a0);
#pragma unroll
        for (int i = 0; i < 16; ++i) a1 = fma(w1d[i], win[(j + 17 + i) & 31], a1);
#pragma unroll
        for (int i = 0; i < 32; ++i) a2 = fma(w2d[i], win[(j + 1 + i) & 31], a2);
        a0 *= s8; a1 *= 0.25; a2 *= s32;

        const int t = t_start + j;
        // panel store (f32): stream index D = 3*(t&15)+ch; float offset
        // (D>>2)*256 + lane*4 + (D&3). Static per (j, ch).
        float* wpf = w32 + ((size_t)(t >> 4) * 4 + bgi) * 3072 + lane * 4;
        const int D0 = (j & 15) * 3;                        // t&15 == j&15
        wpf[((D0    ) >> 2) * 256 + ((D0    ) & 3)] = (float)(a0 - 0.05);
        wpf[((D0 + 1) >> 2) * 256 + ((D0 + 1) & 3)] = (float)(a1 - 0.05);
        wpf[((D0 + 2) >> 2) * 256 + ((D0 + 2) & 3)] = (float)(a2 - 0.05);

        fr0[j & 15] = (float)a0; fr1[j & 15] = (float)a1; fr2[j & 15] = (float)a2;
        if ((j & 15) == 15) {
            float* d = uf + t_start + (j & ~15);
#pragma unroll
            for (int q = 0; q < 4; ++q) {
                *(float4*)(d + 4 * q)         = ((float4*)fr0)[q];
                *(float4*)(d + T + 4 * q)     = ((float4*)fr1)[q];
                *(float4*)(d + 2 * T + 4 * q) = ((float4*)fr2)[q];
            }
        }
    }
}

// ---------------------------------------------------------------------------
// Scan: speculative chunked LIF-WTA, one (chain, chunk) per lane, 1 wave/CU.
// f64 state, f32 W. LDS-DMA triple buffer (3 x 12 KB), counted vmcnt.
// XCD-aware block remap: XCD k runs (bg 0..3) x (c in [8k, 8k+8)) so
// co-resident blocks share 32/48 of their warm groups in the 4 MB XCD-L2.
// ---------------------------------------------------------------------------
__global__ __launch_bounds__(64, 1) void scan_kernel(
    const float* __restrict__ w32,
    float* __restrict__ s_out)        // [B][K][T] f32
{
    // blockIdx -> XCD is round-robin (bid & 7 on 8 XCDs); cluster c-ranges.
    const int phys = blockIdx.x;
    const int xcd  = phys & 7;
    const int slot = phys >> 3;            // 32 blocks per XCD
    const int c    = 8 * xcd + (slot & 7); // contiguous chunk range per XCD
    const int bg   = slot >> 3;
    const int lane = threadIdx.x;
    const int chain = bg * 64 + lane;

    const int t_emit = c * CHUNK;
    const int t_w    = (t_emit >= WARM) ? (t_emit - WARM) : 0;
    const int warm_g = (t_emit - t_w) >> 4;     // 0, 16, or 32
    const int n_g    = warm_g + (CHUNK >> 4);   // 16, 32, or 48
    const int tw16   = t_w >> 4;

    float* sb = s_out + (size_t)chain * (3 * T);

    // 3 slabs x 12 KB (one 16-step group each) = 36 KB LDS ring.
    __shared__ float4 lbuf[3 * 768];

    double m0 = -1.0, m1 = -1.0, m2 = -1.0;     // v=0 -> m=-1 exactly

// Counted-vmcnt wait (T4). N = number of vmem ops issued after slab s's
// last DMA load; vmcnt retires in order, so outstanding<=N => slab landed.
#define WAITN(N) asm volatile("s_waitcnt vmcnt(" #N ")" ::: "memory")

// DMA one 12 KB group into slab s: 12 instrs, each 64 lanes x 16 B.
// LDS dest = wave-uniform base (+ lane*16 by HW) == linear image of the
// global slab. WAR safety vs the ds_reads of the slab being overwritten:
// every rf value is consumed by VALU before this point, and the compiler's
// use-waits drain those ds_reads; no explicit lgkm fence needed.
#define LOADDMA(s, gg) do {                                                   \
    const float4* _src = (const float4*)(w32 +                                \
        ((size_t)(tw16 + (gg)) * 4 + bg) * 3072) + lane;                      \
    _Pragma("unroll")                                                         \
    for (int _q = 0; _q < 12; ++_q)                                           \
        __builtin_amdgcn_global_load_lds(                                     \
            (const __attribute__((address_space(1))) void*)(const void*)      \
                (_src + (size_t)_q * 64),                                     \
            (__attribute__((address_space(3))) void*)(void*)                  \
                (&lbuf[(s) * 768 + _q * 64]),                                 \
            16, 0, 0);                                                        \
} while (0)

#define STEP(W0, W1, W2, O0, O1, O2) do {                               \
    const double M0 = fma(0.95, m0, (W0));                              \
    const double M1 = fma(0.95, m1, (W1));                              \
    const double M2 = fma(0.95, m2, (W2));                              \
    const bool c01 = (M0 >= M1);                                        \
    const bool c02 = (M0 >= M2);                                        \
    const bool c12 = (M1 >= M2);                                        \
    const bool f0  = (M0 >= 0.0);                                       \
    const bool f1  = (M1 >= 0.0);                                       \
    const bool f2  = (M2 >= 0.0);                                       \
    const bool s0 = c01 & c02 & f0;          /* first-index argmax */   \
    const bool s1 = (!c01) & c12 & f1;                                  \
    const bool s2 = (!c02) & (!c12) & f2;                               \
    m0 = s0 ? M0 - 1.0 : M0;                                            \
    m1 = s1 ? M1 - 1.0 : M1;                                            \
    m2 = s2 ? M2 - 1.0 : M2;                                            \
    (O0) = s0 ? 1.0f : 0.0f;                                            \
    (O1) = s1 ? 1.0f : 0.0f;                                            \
    (O2) = s2 ? 1.0f : 0.0f;                                            \
} while (0)

// Compile-time component select keeps _rf in registers after full unroll.
#define GETW(d) ( ((d) & 3) == 0 ? _rf[(d) >> 2].x                      \
                : ((d) & 3) == 1 ? _rf[(d) >> 2].y                      \
                : ((d) & 3) == 2 ? _rf[(d) >> 2].z                      \
                :                  _rf[(d) >> 2].w )

// Per-phase wait-count derivation (issue order: prologue L0,L1,L2; phase p:
// WAIT -> 12 ds_read_b128 -> compute -> stores(p) -> L(p+3)). Newer-than-L(p)
// = 12*[p+1<n_g] + 12*[p+2<n_g] + 12*emit(p-1) + 12*emit(p-2):
//   warm steady / first emit: 24 | p==warm_g+1: 36 | emit steady: 48
//   p == n_g-2: 12+24 = 36 | p == n_g-1: 24
#define BODY(s, pp) do {                                                      \
    if ((pp) < n_g) {                                                         \
        if ((pp) == n_g - 1)            WAITN(24);                            \
        else if ((pp) == n_g - 2)       WAITN(36);                            \
        else if ((pp) >= warm_g + 2)    WAITN(48);                            \
        else if ((pp) == warm_g + 1)    WAITN(36);                            \
        else                            WAITN(24);                            \
        const float4* _lp = lbuf + (s) * 768 + lane;                          \
        float4 _rf[12];                                                       \
        _Pragma("unroll")                                                     \
        for (int _q = 0; _q < 12; ++_q) _rf[_q] = _lp[(size_t)_q * 64];       \
        float sp0[16], sp1[16], sp2[16];                                      \
        _Pragma("unroll")                                                     \
        for (int _j = 0; _j < 16; ++_j) {                                     \
            const int _d0 = 3 * _j;                                           \
            const double _W0 = (double)GETW(_d0);                             \
            const double _W1 = (double)GETW(_d0 + 1);                         \
            const double _W2 = (double)GETW(_d0 + 2);                         \
            STEP(_W0, _W1, _W2, sp0[_j], sp1[_j], sp2[_j]);                   \
        }                                                                     \
        if ((pp) >= warm_g) {                                                 \
            float* _d = sb + t_w + (size_t)(pp) * 16;                         \
            _Pragma("unroll")                                                 \
            for (int _q = 0; _q < 4; ++_q) {                                  \
                *(float4*)(_d + 4*_q)         = ((float4*)sp0)[_q];           \
                *(float4*)(_d + T + 4*_q)     = ((float4*)sp1)[_q];           \
                *(float4*)(_d + 2*T + 4*_q)   = ((float4*)sp2)[_q];           \
            }                                                                 \
        }                                                                     \
        if ((pp) + 3 < n_g) LOADDMA(s, (pp) + 3);                             \
    }                                                                         \
} while (0)

    LOADDMA(0, 0);
    LOADDMA(1, 1);
    LOADDMA(2, 2);
    for (int p = 0; p < n_g; p += 3) {
        BODY(0, p);
        BODY(1, p + 1);
        BODY(2, p + 2);
    }

#undef BODY
#undef GETW
#undef STEP
#undef LOADDMA
#undef WAITN
}

// ---------------------------------------------------------------------------
extern "C" void kernel_launch(void* const* d_in, const int* in_sizes, int n_in,
                              void* d_out, int out_size, void* d_ws, size_t ws_size,
                              hipStream_t stream)
{
    const float* x  = (const float*)d_in[0];
    const float* w0 = (const float*)d_in[1];
    const float* w1 = (const float*)d_in[2];
    const float* w2 = (const float*)d_in[3];
    // d_in[4] = y (unused by the reference outputs)

    float* out   = (float*)d_out;
    float* u_out = out;                        // [B][K][T]
    float* s_out = out + (size_t)B * K * T;    // [B][K][T]

    float* w32 = (float*)d_ws;                 // 50.3 MB f32 panel (ws >= 100 MB)

    conv_kernel<<<(B / 64) * (T / CBT), 256, 0, stream>>>(x, w0, w1, w2, u_out, w32);
    scan_kernel<<<B, 64, 0, stream>>>(w32, s_out);
}

// Round 4
// 216.969 us; speedup vs baseline: 1.1815x; 1.1815x over previous
//
#include <hip/hip_runtime.h>
#include <math.h>

// Problem constants (match reference)
constexpr int B = 256;
constexpr int T = 16384;
constexpr int K = 3;

// Speculative chunking: emit 256 steps after 512-step warm-up (proven R5/R6).
constexpr int CHUNK = 256;
constexpr int WARM  = 512;

// Conv tiling: 64 chains x 128 timesteps per block, 4 waves x 32 t each.
constexpr int CBT = 128;
constexpr int CWT = 32;

// R10 theory: CDNA has ONE vmem counter; every phase's s_waitcnt vmcnt(N)
// therefore waits (in retire order) on the previous emit phases' s_out
// stores. Those stores scatter 64 lanes x 16 B to 64 lines 192 KB apart
// (768 line-transactions per emit phase) -> store retire, not load service,
// is the ~4.4k cy/phase gate that was identical across R0/R7/R8 load schemes.
// Fix: stage the emit block in LDS, transpose, and store full 64 B lines
// (192 transactions). Conv panel stores get the same treatment via register
// batching (PPUT: 1 KB contiguous per instruction).
//
// w32 panel layout [T/16][4 bg][12 q][64 lane] x 16B (float4):
// float4 q of lane i = stream floats (4q..4q+3) of chain (bg*64+i), stream
// ordered (t_local 0..15) x (ch 0..2). Lane-coalesced on both sides.

// ---------------------------------------------------------------------------
// Conv: causal k=8/16/32 in f64 (same tap order / fma / scale as R2-R8).
// Panel stores register-batched into float4 (fully coalesced 1 KB/instr).
// Numeric path and u_out stores unchanged from the passing R8.
// ---------------------------------------------------------------------------
__global__ __launch_bounds__(256, 2) void conv_kernel(
    const float* __restrict__ x,
    const float* __restrict__ w0f,
    const float* __restrict__ w1f,
    const float* __restrict__ w2f,
    float*  __restrict__ u_out,   // [B][K][T] f32
    float*  __restrict__ w32)     // panel layout above
{
    const int blk = blockIdx.x;            // 512 blocks
    const int bgi = blk >> 7;              // 4 b-tiles
    const int t0  = (blk & 127) * CBT;     // 128 t-tiles
    const int b0  = bgi * 64;
    const int tid = threadIdx.x;

    __shared__ float sx[64][164];          // cols t0-32 .. t0+127, +4 pad
    for (int k = tid; k < 64 * 40; k += 256) {
        const int r  = k / 40;
        const int c4 = k - r * 40;
        const int g  = t0 - 32 + 4 * c4;
        float4 v = make_float4(0.f, 0.f, 0.f, 0.f);
        if (g >= 0) v = *(const float4*)(x + (size_t)(b0 + r) * T + g);
        *(float4*)&sx[r][4 * c4] = v;
    }
    __syncthreads();

    const int lane    = tid & 63;
    const int w       = tid >> 6;
    const int t_start = t0 + CWT * w;

    double w0d[8], w1d[16], w2d[32];
#pragma unroll
    for (int i = 0; i < 8; ++i)  w0d[i] = (double)w0f[i];
#pragma unroll
    for (int i = 0; i < 16; ++i) w1d[i] = (double)w1f[i];
#pragma unroll
    for (int i = 0; i < 32; ++i) w2d[i] = (double)w2f[i];

    // ring window: win[t & 31] = x[chain][t]
    double win[32];
#pragma unroll
    for (int k = 1; k < 32; ++k) win[k] = (double)sx[lane][CWT * w + k];

    const double s8  = 1.0 / sqrt(8.0);
    const double s32 = 1.0 / sqrt(32.0);

    float fr0[16], fr1[16], fr2[16];
    float4 pf;                              // panel float4 batcher
    float* uf = u_out + (size_t)(b0 + lane) * (3 * T);

// Put stream value v at stream slot D (compile-time after unroll); flush the
// float4 to panel slot q=D>>2 when the last component lands. Store instr:
// 64 lanes x 16 B contiguous (layout is [q][lane] float4) = 1 KB coalesced.
// D resets every 16 j in lockstep with wq's (t>>4) group, so every flush
// stays inside its group (D in [0,47], flushes at D=3,7,...,47).
#define PPUT(v, D) do {                                                       \
    const float _pv = (v);                                                    \
    if (((D) & 3) == 0) pf.x = _pv;                                           \
    else if (((D) & 3) == 1) pf.y = _pv;                                      \
    else if (((D) & 3) == 2) pf.z = _pv;                                      \
    else {                                                                    \
        pf.w = _pv;                                                           \
        *(float4*)(wq + ((D) >> 2) * 256) = pf;                               \
    }                                                                         \
} while (0)

#pragma unroll
    for (int j = 0; j < CWT; ++j) {
        win[j & 31] = (double)sx[lane][CWT * w + 32 + j];   // push x[t]
        double a0 = 0.0, a1 = 0.0, a2 = 0.0;
#pragma unroll
        for (int i = 0; i < 8; ++i)  a0 = fma(w0d[i], win[(j + 25 + i) & 31], a0);
#pragma unroll
        for (int i = 0; i < 16; ++i) a1 = fma(w1d[i], win[(j + 17 + i) & 31], a1);
#pragma unroll
        for (int i = 0; i < 32; ++i) a2 = fma(w2d[i], win[(j + 1 + i) & 31], a2);
        a0 *= s8; a1 *= 0.25; a2 *= s32;

        const int t = t_start + j;
        float* wq = w32 + ((size_t)(t >> 4) * 4 + bgi) * 3072 + lane * 4;
        const int D0 = (j & 15) * 3;                        // t&15 == j&15
        PPUT((float)(a0 - 0.05), D0);
        PPUT((float)(a1 - 0.05), D0 + 1);
        PPUT((float)(a2 - 0.05), D0 + 2);

        fr0[j & 15] = (float)a0; fr1[j & 15] = (float)a1; fr2[j & 15] = (float)a2;
        if ((j & 15) == 15) {
            float* d = uf + t_start + (j & ~15);
#pragma unroll
            for (int q = 0; q < 4; ++q) {
                *(float4*)(d + 4 * q)         = ((float4*)fr0)[q];
                *(float4*)(d + T + 4 * q)     = ((float4*)fr1)[q];
                *(float4*)(d + 2 * T + 4 * q) = ((float4*)fr2)[q];
            }
        }
    }
#undef PPUT
}

// ---------------------------------------------------------------------------
// Scan: speculative chunked LIF-WTA, one (chain, chunk) per lane, 1 wave/CU.
// f64 state, f32 W. LDS-DMA triple buffer (proven R8) + NEW: s_out emit goes
// through a padded LDS transpose so each store instruction writes 16 full
// 64 B lines (4-lane groups cover one (chain, channel) line). LOADDMA is
// issued BEFORE the emit staging, so the R8-proven wait table still holds.
// ---------------------------------------------------------------------------
__global__ __launch_bounds__(64, 1) void scan_kernel(
    const float* __restrict__ w32,
    float* __restrict__ s_out)        // [B][K][T] f32
{
    // blockIdx -> XCD is round-robin (bid & 7 on 8 XCDs); cluster c-ranges.
    const int phys = blockIdx.x;
    const int xcd  = phys & 7;
    const int slot = phys >> 3;            // 32 blocks per XCD
    const int c    = 8 * xcd + (slot & 7); // contiguous chunk range per XCD
    const int bg   = slot >> 3;
    const int lane = threadIdx.x;

    const int t_emit = c * CHUNK;
    const int t_w    = (t_emit >= WARM) ? (t_emit - WARM) : 0;
    const int warm_g = (t_emit - t_w) >> 4;     // 0, 16, or 32
    const int n_g    = warm_g + (CHUNK >> 4);   // 16, 32, or 48
    const int tw16   = t_w >> 4;

    // 3 slabs x 12 KB (one 16-step group each) = 36 KB LDS ring.
    __shared__ float4 lbuf[3 * 768];
    // store-transpose stage: 12 slabs (k*4+q) x 64 chains, +1 float4 pad per
    // slab (slab stride 1040 B == 16 mod 128 -> read side conflict-free).
    __shared__ float4 sstage[12 * 65];

    double m0 = -1.0, m1 = -1.0, m2 = -1.0;     // v=0 -> m=-1 exactly

// Counted-vmcnt wait. N is a guaranteed lower bound on the number of vmem
// ops issued after the awaited slab's last DMA load (stores are pinned
// inside their phase window by the "memory" clobbers; ops in the same
// window as the slab's loads are never counted).
#define WAITN(N) do {                                                   \
    asm volatile("s_waitcnt vmcnt(" #N ")" ::: "memory");               \
    __builtin_amdgcn_sched_barrier(0);                                  \
} while (0)

// DMA one 12 KB group into slab s: 12 instrs, each 64 lanes x 16 B.
#define LOADDMA(s, gg) do {                                                   \
    const float4* _src = (const float4*)(w32 +                                \
        ((size_t)(tw16 + (gg)) * 4 + bg) * 3072) + lane;                      \
    _Pragma("unroll")                                                         \
    for (int _q = 0; _q < 12; ++_q)                                           \
        __builtin_amdgcn_global_load_lds(                                     \
            (const __attribute__((address_space(1))) void*)(const void*)      \
                (_src + (size_t)_q * 64),                                     \
            (__attribute__((address_space(3))) void*)(void*)                  \
                (&lbuf[(s) * 768 + _q * 64]),                                 \
            16, 0, 0);                                                        \
} while (0)

#define STEP(W0, W1, W2, O0, O1, O2) do {                               \
    const double M0 = fma(0.95, m0, (W0));                              \
    const double M1 = fma(0.95, m1, (W1));                              \
    const double M2 = fma(0.95, m2, (W2));                              \
    const bool c01 = (M0 >= M1);                                        \
    const bool c02 = (M0 >= M2);                                        \
    const bool c12 = (M1 >= M2);                                        \
    const bool f0  = (M0 >= 0.0);                                       \
    const bool f1  = (M1 >= 0.0);                                       \
    const bool f2  = (M2 >= 0.0);                                       \
    const bool s0 = c01 & c02 & f0;          /* first-index argmax */   \
    const bool s1 = (!c01) & c12 & f1;                                  \
    const bool s2 = (!c02) & (!c12) & f2;                               \
    m0 = s0 ? M0 - 1.0 : M0;                                            \
    m1 = s1 ? M1 - 1.0 : M1;                                            \
    m2 = s2 ? M2 - 1.0 : M2;                                            \
    (O0) = s0 ? 1.0f : 0.0f;                                            \
    (O1) = s1 ? 1.0f : 0.0f;                                            \
    (O2) = s2 ? 1.0f : 0.0f;                                            \
} while (0)

// Compile-time component select keeps _rf in registers after full unroll.
#define GETW(d) ( ((d) & 3) == 0 ? _rf[(d) >> 2].x                      \
                : ((d) & 3) == 1 ? _rf[(d) >> 2].y                      \
                : ((d) & 3) == 2 ? _rf[(d) >> 2].z                      \
                :                  _rf[(d) >> 2].w )

// Per-phase wait counts (R8-proven; issue order: prologue L0,L1,L2; phase p:
// WAIT -> ds reads -> compute -> L(p+3) -> staged stores(p)). Lower bound on
// newer-than-L(p) = 12*[p+1<n_g] + 12*[p+2<n_g] + 12*emit(p-1) + 12*emit(p-2)
// (stores(p-1)/(p-2) lie in whole windows after L(p); stores(p-3) shares
// L(p)'s window so it is conservatively NOT counted):
//   warm steady / first emit: 24 | p==warm_g+1: 36 | emit steady: 48
//   p == n_g-2: 36 | p == n_g-1: 24
#define BODY(s, pp) do {                                                      \
    if ((pp) < n_g) {                                                         \
        if ((pp) == n_g - 1)            WAITN(24);                            \
        else if ((pp) == n_g - 2)       WAITN(36);                            \
        else if ((pp) >= warm_g + 2)    WAITN(48);                            \
        else if ((pp) == warm_g + 1)    WAITN(36);                            \
        else                            WAITN(24);                            \
        const float4* _lp = lbuf + (s) * 768 + lane;                          \
        float4 _rf[12];                                                       \
        _Pragma("unroll")                                                     \
        for (int _q = 0; _q < 12; ++_q) _rf[_q] = _lp[(size_t)_q * 64];       \
        float sp0[16], sp1[16], sp2[16];                                      \
        _Pragma("unroll")                                                     \
        for (int _j = 0; _j < 16; ++_j) {                                     \
            const int _d0 = 3 * _j;                                           \
            const double _W0 = (double)GETW(_d0);                             \
            const double _W1 = (double)GETW(_d0 + 1);                         \
            const double _W2 = (double)GETW(_d0 + 2);                         \
            STEP(_W0, _W1, _W2, sp0[_j], sp1[_j], sp2[_j]);                   \
        }                                                                     \
        if ((pp) + 3 < n_g) LOADDMA(s, (pp) + 3);                             \
        if ((pp) >= warm_g) {                                                 \
            /* transpose via LDS: lane (=chain) writes its 12 float4s ... */  \
            _Pragma("unroll")                                                 \
            for (int _q = 0; _q < 4; ++_q) {                                  \
                sstage[(0 * 4 + _q) * 65 + lane] = ((float4*)sp0)[_q];        \
                sstage[(1 * 4 + _q) * 65 + lane] = ((float4*)sp1)[_q];        \
                sstage[(2 * 4 + _q) * 65 + lane] = ((float4*)sp2)[_q];        \
            }                                                                 \
            asm volatile("s_waitcnt lgkmcnt(0)" ::: "memory");                \
            __builtin_amdgcn_sched_barrier(0);                                \
            /* ... then 4-lane groups store full 64 B lines: instr (k,g)  */  \
            /* writes chains g*16..g*16+15, channel k, 16 floats each.    */  \
            const int _t = t_w + (pp) * 16;                                   \
            _Pragma("unroll")                                                 \
            for (int _k = 0; _k < 3; ++_k) {                                  \
                _Pragma("unroll")                                             \
                for (int _g = 0; _g < 4; ++_g) {                              \
                    const float4 _v =                                         \
                        sstage[(_k * 4 + (lane & 3)) * 65 + _g * 16 + (lane >> 2)]; \
                    float* _dst = s_out                                       \
                        + (size_t)(bg * 64 + _g * 16 + (lane >> 2)) * (3 * T) \
                        + (size_t)_k * T + _t + (lane & 3) * 4;               \
                    *(float4*)_dst = _v;                                      \
                }                                                             \
            }                                                                 \
        }                                                                     \
    }                                                                         \
} while (0)

    LOADDMA(0, 0);
    LOADDMA(1, 1);
    LOADDMA(2, 2);
    for (int p = 0; p < n_g; p += 3) {
        BODY(0, p);
        BODY(1, p + 1);
        BODY(2, p + 2);
    }

#undef BODY
#undef GETW
#undef STEP
#undef LOADDMA
#undef WAITN
}

// ---------------------------------------------------------------------------
extern "C" void kernel_launch(void* const* d_in, const int* in_sizes, int n_in,
                              void* d_out, int out_size, void* d_ws, size_t ws_size,
                              hipStream_t stream)
{
    const float* x  = (const float*)d_in[0];
    const float* w0 = (const float*)d_in[1];
    const float* w1 = (const float*)d_in[2];
    const float* w2 = (const float*)d_in[3];
    // d_in[4] = y (unused by the reference outputs)

    float* out   = (float*)d_out;
    float* u_out = out;                        // [B][K][T]
    float* s_out = out + (size_t)B * K * T;    // [B][K][T]

    float* w32 = (float*)d_ws;                 // 50.3 MB f32 panel (ws >= 100 MB)

    conv_kernel<<<(B / 64) * (T / CBT), 256, 0, stream>>>(x, w0, w1, w2, u_out, w32);
    scan_kernel<<<B, 64, 0, stream>>>(w32, s_out);
}